// Round 6
// baseline (366.021 us; speedup 1.0000x reference)
//
#include <hip/hip_runtime.h>

#define NID  16
#define BB   4
#define HH   192
#define WW   192
#define DHW  1179648          // 32*192*192
#define KB   256              // lovasz buckets over e in [0,2]
#define NCOPY 8               // global histogram replicas (line-RMW chain /8)

// pass1: grid (256, BB); block chunk = 24 rows; wave-pair = 12 rows = 2304 vox
#define P1_ROWS   24
#define P1_ITERS  36          // 2304 / 64

// pass3 chunking: 768 blocks (3/CU), chunk 6144 voxels, 6 subs of 1024
#define P3_CHUNKS 192
#define P3_CHUNK  6144        // DHW / 192
#define SUBT      6
#define SUBN      1024        // P3_CHUNK / 6
#define SUBIT     4           // SUBN / 256

// workspace layout (float indices)
#define WS_STATS 0            // [64][8]: cnt, Sx, Sy, Sz, s0, s1, s2, ssq
#define WS_BG8   512          // [4][8] spread slots
#define WS_SEED8 544          // [4][8]
#define WS_INSTL 576          // [64]
#define WS_CTR   640          // [1] completion counter (pass4 last-block)
#define WS_HIST  648          // [NCOPY][64][2][KB] floats
#define WS_TOTAL (648 + NCOPY*64*2*KB)

__device__ __forceinline__ float ftanh(float x) {
    float t = __expf(2.f * x);
    return 1.f - 2.f / (t + 1.f);
}
__device__ __forceinline__ float fsigmoid(float x) {
    return 1.f / (1.f + __expf(-x));
}
__device__ __forceinline__ float wred(float v) {
    for (int off = 32; off > 0; off >>= 1) v += __shfl_down(v, off, 64);
    return v;
}
// xyzm is a linspace stack: compute from flat index
__device__ __forceinline__ void xyz_of(int v, float& x, float& y, float& z) {
    int w = v % WW;
    int t = v / WW;
    int h = t % HH;
    int d = t / HH;
    x = (float)w * (1.f / 191.f);
    y = (float)h * (1.f / 191.f);
    z = (float)d * (1.f / 31.f);
}

#define REP8(M) M(0) M(1) M(2) M(3) M(4) M(5) M(6) M(7)

// ---------------- pass 1: per-(b,id) masked stats + bg_seed ----------------
// r5 rework: ONE wave accumulates all 8 stats for its 8 ids (48 named-scalar
// regs, r3-proven promotion). Waves 0/1 (ids 0-7 / 8-15) stream rows 0-11 of
// the block chunk; waves 2/3 stream rows 12-23. Each voxel is streamed by 2
// waves (was 4) -> load instrs and redundant L1/L2 streams halved.
// Epilogue unchanged: LDS partials -> one coalesced 128-float global atomic.
__global__ __launch_bounds__(256) void pass1_stats(
    const float* __restrict__ pred, const int* __restrict__ inst,
    const int* __restrict__ labels, float* __restrict__ ws)
{
    __shared__ float part[2][128];      // [wave-pair][id 0..15][st 0..7]
    const int b     = blockIdx.y;
    const int tid   = threadIdx.x;
    const int wv    = tid >> 6;         // 0..3
    const int lane  = tid & 63;
    const int wpair = wv >> 1;          // voxel sub-range
    const int half  = wv & 1;           // 0: ids 1..8, 1: ids 9..16
    const int idb0  = half * 8;         // 0-based first id

    const float* p3 = pred + (size_t)(b * 7 + 3) * DHW;
    const int*   ib = inst   + (size_t)b * DHW;
    const int*   lb = labels + (size_t)b * DHW;
    const int row0 = blockIdx.x * P1_ROWS + wpair * 12;

    // packed geo: G0 = Sw | cnt<<17, G1 = Sh | Sd<<17 (36 iters: cnt<=36,
    // Sw,Sh<=6876<2^17, Sd<=1116<2^15 -> exact)
    unsigned G00=0u,G01=0u,G02=0u,G03=0u,G04=0u,G05=0u,G06=0u,G07=0u;
    unsigned G10=0u,G11=0u,G12=0u,G13=0u,G14=0u,G15=0u,G16=0u,G17=0u;
    float SA0=0.f,SA1=0.f,SA2=0.f,SA3=0.f,SA4=0.f,SA5=0.f,SA6=0.f,SA7=0.f;
    float SB0=0.f,SB1=0.f,SB2=0.f,SB3=0.f,SB4=0.f,SB5=0.f,SB6=0.f,SB7=0.f;
    float SC0=0.f,SC1=0.f,SC2=0.f,SC3=0.f,SC4=0.f,SC5=0.f,SC6=0.f,SC7=0.f;
    float SD0=0.f,SD1=0.f,SD2=0.f,SD3=0.f,SD4=0.f,SD5=0.f,SD6=0.f,SD7=0.f;
    float bgacc = 0.f;

    for (int it = 0; it < P1_ITERS; ++it) {
        const int seg = it % 3, r = it / 3;     // uniform (SALU)
        const int row = row0 + r;
        const int w   = seg * 64 + lane;
        const int v   = row * WW + w;
        const int id  = ib[v];
        const float s0 = p3[v], s1 = p3[DHW + v], s2 = p3[2 * DHW + v];
        const float sq = s0 * s0 + s1 * s1 + s2 * s2;
        if (half == 0) {
            const float seed = fsigmoid(p3[3 * DHW + v]);
            if (lb[v] == 0) bgacc += seed * seed;
        }
        const unsigned p0 = (unsigned)w | (1u << 17);
        const unsigned p1 = (unsigned)(row % HH) | ((unsigned)(row / HH) << 17);
        const int idx = id - 1 - idb0;
        #define ACC(Q) { const bool e = (idx == Q); \
            G0##Q += e ? p0 : 0u; G1##Q += e ? p1 : 0u; \
            const float m = e ? 1.f : 0.f; \
            SA##Q = fmaf(m, s0, SA##Q); SB##Q = fmaf(m, s1, SB##Q); \
            SC##Q = fmaf(m, s2, SC##Q); SD##Q = fmaf(m, sq, SD##Q); }
        REP8(ACC)
        #undef ACC
    }

    #define GRED(Q) { \
        float c  = wred((float)(G0##Q >> 17)); \
        float sx = wred((float)(G0##Q & 0x1FFFFu) * (1.f / 191.f)); \
        float sy = wred((float)(G1##Q & 0x1FFFFu) * (1.f / 191.f)); \
        float sz = wred((float)(G1##Q >> 17)      * (1.f / 31.f)); \
        float r0 = wred(SA##Q), r1 = wred(SB##Q); \
        float r2 = wred(SC##Q), r3 = wred(SD##Q); \
        if (lane == 0) { float* pp = &part[wpair][(idb0 + Q) * 8]; \
            pp[0]=c; pp[1]=sx; pp[2]=sy; pp[3]=sz; \
            pp[4]=r0; pp[5]=r1; pp[6]=r2; pp[7]=r3; } }
    REP8(GRED)
    #undef GRED

    if (half == 0) {
        const float r = wred(bgacc);
        if (lane == 0) atomicAdd(&ws[WS_BG8 + b * 8 + (blockIdx.x & 7)], r);
    }
    __syncthreads();
    // one coalesced atomic covering 128 consecutive floats (8 lines/block)
    if (tid < 128) {
        const float pv = part[0][tid] + part[1][tid];
        if (pv != 0.f) atomicAdd(&ws[WS_STATS + b * 128 + tid], pv);
    }
}

// ---------------- pass 3: staged se + count-only histograms ----------------
// r5 counter-driven changes:
//  (a) phases 4 -> 2 (8 ids/phase): sev b128 re-reads and ctrs reloads halved.
//  (b) global merge -> NCOPY=8 line-disjoint copies (blockIdx.x&7): per-line
//      RMW chain depth 192 -> 24 (r5 WRITE_SIZE=24MB flagged the old chains).
__global__ __launch_bounds__(256) void pass3_hist(
    const float* __restrict__ pred, const int* __restrict__ inst,
    float* __restrict__ ws)
{
    __shared__ float4 sev[SUBN];              // 16.4 KB (se0,se1,se2,seed|id)
    __shared__ unsigned cntFB[2][NID][KB + 1];// 32.9 KB: x2 replicas, padded
    __shared__ float ctrs[NID][8];
    __shared__ float sred[4];

    const int b   = blockIdx.y;
    const int tid = threadIdx.x;
    const int rep = (tid >> 5) & 1;           // half-wave replica
    const int rot = tid & 15;                 // per-lane id rotation (16-way)

    for (int i = tid; i < 2 * NID * (KB + 1); i += 256) ((unsigned*)cntFB)[i] = 0u;
    if (tid < NID) {
        const float* s = ws + WS_STATS + (size_t)(b * NID + tid) * 8;
        const float cnt = s[0];
        const float safe = fmaxf(cnt, 1.f);
        const float m0 = s[4] / safe, m1 = s[5] / safe, m2 = s[6] / safe;
        ctrs[tid][0] = s[1] / safe;
        ctrs[tid][1] = s[2] / safe;
        ctrs[tid][2] = s[3] / safe;
        ctrs[tid][3] = __expf(10.f * m0);
        ctrs[tid][4] = __expf(10.f * m1);
        ctrs[tid][5] = __expf(10.f * m2);
        ctrs[tid][6] = 0.f;
        ctrs[tid][7] = (cnt > 0.f) ? 1.f : 0.f;
    }
    __syncthreads();

    const float* pb = pred + (size_t)b * 7 * DHW;
    const int*   ib = inst + (size_t)b * DHW;

    float sacc = 0.f;
    const int base0 = blockIdx.x * P3_CHUNK;

    for (int sub = 0; sub < SUBT; ++sub) {
        const int vb = base0 + sub * SUBN;
        // ---- phase A: stage se / seed / id ----
        for (int it = 0; it < SUBIT; ++it) {
            const int i = it * 256 + tid;
            const int v = vb + i;
            float x, y, z; xyz_of(v, x, y, z);
            const float se0 = ftanh(pb[v])           + x;
            const float se1 = ftanh(pb[DHW + v])     + y;
            const float se2 = ftanh(pb[2 * DHW + v]) + z;
            const float seed = fsigmoid(pb[6 * DHW + v]);
            const unsigned id = (unsigned)ib[v];
            // pack instance id into low 8 mantissa bits of seed (|err| < 2^-16)
            const unsigned sw = (__float_as_uint(seed) & ~0xFFu) | id;
            sev[i] = make_float4(se0, se1, se2, __uint_as_float(sw));
        }
        __syncthreads();
        // ---- phase B: 2 passes x 8 slots; lane-rotated over ALL 16 ids ----
        for (int p = 0; p < 2; ++p) {
            float cx[8], cy[8], cz[8], e0[8], e1[8], e2[8];
            int ip1[8];
            unsigned* rowp[8];
            #pragma unroll
            for (int j = 0; j < 8; ++j) {
                const int iid = (p * 8 + j + rot) & 15;
                ip1[j]  = iid + 1;
                rowp[j] = &cntFB[rep][iid][0];
                cx[j] = ctrs[iid][0]; cy[j] = ctrs[iid][1]; cz[j] = ctrs[iid][2];
                e0[j] = ctrs[iid][3]; e1[j] = ctrs[iid][4]; e2[j] = ctrs[iid][5];
            }
            for (int it = 0; it < SUBIT; ++it) {
                const int i = it * 256 + tid;
                const float4 sv = sev[i];
                const unsigned sw = __float_as_uint(sv.w);
                const int id = (int)(sw & 0xFFu);
                const float seed = sv.w;
                #pragma unroll
                for (int j = 0; j < 8; ++j) {
                    const float d0 = sv.x - cx[j];
                    const float d1 = sv.y - cy[j];
                    const float d2 = sv.z - cz[j];
                    const float q2 = d0 * d0 * e0[j] + d1 * d1 * e1[j] + d2 * d2 * e2[j];
                    const float dist = __expf(-q2);
                    const bool m = (id == ip1[j]);
                    const float t256 = dist * 256.f;
                    const float kf = m ? (256.f - t256) : t256;
                    int k = (int)kf;
                    k = min(max(k, 0), KB - 1);
                    // BG in bucket 0 contributes exactly 0 -> skip
                    const unsigned val = m ? 1u : (k ? 0x10000u : 0u);
                    if (m) { const float ds = seed - dist; sacc += ds * ds; }
                    if (val) atomicAdd(rowp[j] + k, val);
                }
            }
        }
        __syncthreads();   // also guards cntFB before the merge below
    }

    // merge packed LDS counts (both replicas) -> global float histogram COPY
    float* gh = ws + WS_HIST + (size_t)((blockIdx.x & (NCOPY - 1)) * 64) * 2 * KB;
    for (int i = tid; i < NID * KB; i += 256) {
        const int iid = i >> 8, k = i & (KB - 1);
        const unsigned c = cntFB[0][iid][k] + cntFB[1][iid][k];  // fields < 2^15
        float* basep = gh + (size_t)(b * NID + iid) * 2 * KB;
        const float cf = (float)(c & 0xFFFFu);
        const float cb = (float)(c >> 16);
        if (cf != 0.f) atomicAdd(&basep[k], cf);
        if (cb != 0.f) atomicAdd(&basep[KB + k], cb);
    }
    // per-batch seed loss reduce (spread over 8 slots)
    float v = sacc;
    for (int off = 32; off > 0; off >>= 1) v += __shfl_down(v, off, 64);
    if ((tid & 63) == 0) sred[tid >> 6] = v;
    __syncthreads();
    if (tid == 0)
        atomicAdd(&ws[WS_SEED8 + b * 8 + (blockIdx.x & 7)],
                  sred[0] + sred[1] + sred[2] + sred[3]);
}

// ------- pass 4: lovasz from count histograms + fused final assembly -------
__global__ __launch_bounds__(256) void pass4_lovasz(float* __restrict__ ws,
                                                    float* __restrict__ out)
{
    const int t = blockIdx.x;    // (b*16 + iid)
    const int j = threadIdx.x;   // j=0 <-> highest-error bucket
    __shared__ float sF[KB], sB[KB];
    __shared__ double red[KB];
    __shared__ int lastBlk;
    __shared__ float pl[3][4];

    const float P = ws[WS_STATS + t * 8];
    const float* ghb = ws + WS_HIST + (size_t)t * 2 * KB;

    const int k = KB - 1 - j;
    float nF = 0.f, nB = 0.f;
    #pragma unroll
    for (int c = 0; c < NCOPY; ++c) {
        nF += ghb[(size_t)c * 64 * 2 * KB + k];
        nB += ghb[(size_t)c * 64 * 2 * KB + KB + k];
    }
    const float mid = ((float)k + 0.5f) * (1.f / 128.f);
    const float rF = nF * mid, rB = nB * mid;

    sF[j] = nF; sB[j] = nB;
    __syncthreads();
    for (int off = 1; off < KB; off <<= 1) {
        float a = 0.f, c = 0.f;
        if (j >= off) { a = sF[j - off]; c = sB[j - off]; }
        __syncthreads();
        sF[j] += a; sB[j] += c;
        __syncthreads();
    }
    double contrib = 0.0;
    if (P > 0.f) {   // exists == (cnt > 0)
        const double Bb = (double)sB[j] - (double)nB;
        const double U0 = (double)P + Bb;
        const double Fafter = (double)sF[j];
        contrib = (double)rF / U0
                + (double)rB * ((double)P - Fafter) / (U0 * (U0 + (double)nB));
    }
    red[j] = contrib;
    __syncthreads();
    for (int off = KB / 2; off > 0; off >>= 1) {
        if (j < off) red[j] += red[j + off];
        __syncthreads();
    }
    if (j == 0) {
        ws[WS_INSTL + t] = (float)red[0];
        __threadfence();                      // release INSTL before counter
        const unsigned old = atomicAdd((unsigned*)&ws[WS_CTR], 1u);
        lastBlk = (old == 63u) ? 1 : 0;
    }
    __syncthreads();
    if (!lastBlk) return;
    __threadfence();                          // acquire other blocks' INSTL

    // ---- final assembly (last block only) ----
    if (j < 4) {
        float obj = 0.f, v = 0.f, i2 = 0.f;
        for (int i = 0; i < NID; ++i) {
            const int u = j * NID + i;
            const float* s = ws + WS_STATS + (size_t)u * 8;
            const float cnt = s[0];
            i2 += ws[WS_INSTL + u];
            if (cnt > 0.f) {
                obj += 1.f;
                const float m0 = s[4] / cnt, m1 = s[5] / cnt, m2 = s[6] / cnt;
                v += (s[7] - cnt * (m0 * m0 + m1 * m1 + m2 * m2)) / (3.f * cnt);
            }
        }
        float sb = 0.f, bg = 0.f;
        for (int q = 0; q < 8; ++q) {
            sb += ws[WS_SEED8 + j * 8 + q];
            bg += ws[WS_BG8   + j * 8 + q];
        }
        const float denom = fmaxf(obj, 1.f);
        pl[0][j] = i2 / denom;
        pl[1][j] = v / denom;
        pl[2][j] = (sb + bg) / (float)DHW;
    }
    __syncthreads();
    if (j == 0) {
        const float linst = (pl[0][0] + pl[0][1] + pl[0][2] + pl[0][3]) * (1.0f / BB);
        const float lvar  = (pl[1][0] + pl[1][1] + pl[1][2] + pl[1][3]) * (10.0f / BB);
        const float lseed = (pl[2][0] + pl[2][1] + pl[2][2] + pl[2][3]) * (1.0f / BB);
        out[0] = linst;
        out[1] = lvar;
        out[2] = lseed;
        out[3] = linst + lvar + lseed;
    }
}

extern "C" void kernel_launch(void* const* d_in, const int* in_sizes, int n_in,
                              void* d_out, int out_size, void* d_ws, size_t ws_size,
                              hipStream_t stream)
{
    const float* pred   = (const float*)d_in[0];
    const int*   inst   = (const int*)  d_in[1];
    const int*   labels = (const int*)  d_in[2];
    // d_in[3] = center_images (unused), d_in[4] = xyzm (computed analytically)
    float* ws  = (float*)d_ws;
    float* out = (float*)d_out;

    hipMemsetAsync(d_ws, 0, (size_t)WS_TOTAL * sizeof(float), stream);

    dim3 grid1(256, BB);
    dim3 grid3(P3_CHUNKS, BB);
    pass1_stats<<<grid1, 256, 0, stream>>>(pred, inst, labels, ws);
    pass3_hist <<<grid3, 256, 0, stream>>>(pred, inst, ws);
    pass4_lovasz<<<64, KB, 0, stream>>>(ws, out);
}

// Round 7
// 365.996 us; speedup vs baseline: 1.0001x; 1.0001x over previous
//
#include <hip/hip_runtime.h>

#define NID  16
#define BB   4
#define HH   192
#define WW   192
#define DHW  1179648          // 32*192*192
#define KB   256              // lovasz buckets over e in [0,2]

// pass1: grid (256, BB); chunk = 24 rows of 192 = 4608 voxels; 72 iters of 64
#define P1_ROWS   24
#define P1_ITERS  72

// pass3 chunking: 768 blocks (3/CU), chunk 6144 voxels, 6 subs of 1024
#define P3_CHUNKS 192
#define P3_CHUNK  6144        // DHW / 192
#define SUBT      6
#define SUBN      1024        // P3_CHUNK / 6
#define SUBIT     4           // SUBN / 256

// workspace layout (float indices)
#define WS_STATS 0            // [64][8]: cnt, Sx, Sy, Sz, s0, s1, s2, ssq
#define WS_BG8   512          // [4][8] spread slots
#define WS_SEED8 544          // [4][8]
#define WS_INSTL 576          // [64]
#define WS_CTR   640          // [1] completion counter (pass4 last-block)
#define WS_HIST  648          // [64][2][KB] floats: cntF, cntB
#define WS_TOTAL (648 + 64*2*KB)

#define LOG2E 1.44269504088896f

__device__ __forceinline__ float ftanh(float x) {
    float t = __expf(2.f * x);
    return 1.f - 2.f / (t + 1.f);
}
__device__ __forceinline__ float fsigmoid(float x) {
    return 1.f / (1.f + __expf(-x));
}
__device__ __forceinline__ float wred(float v) {
    for (int off = 32; off > 0; off >>= 1) v += __shfl_down(v, off, 64);
    return v;
}
// xyzm is a linspace stack: compute from flat index
__device__ __forceinline__ void xyz_of(int v, float& x, float& y, float& z) {
    int w = v % WW;
    int t = v / WW;
    int h = t % HH;
    int d = t / HH;
    x = (float)w * (1.f / 191.f);
    y = (float)h * (1.f / 191.f);
    z = (float)d * (1.f / 31.f);
}

#define REP8(M) M(0) M(1) M(2) M(3) M(4) M(5) M(6) M(7)

// ---------------- pass 1: per-(b,id) masked stats + bg_seed ----------------
// (r5-proven version, ~86 us: 4 waves = (id-half x geo/sigma), named-scalar
// register accumulation, coalesced 128-float atomic epilogue. r6's merged
// variant regressed ~+9 us -> reverted.)
__global__ __launch_bounds__(256) void pass1_stats(
    const float* __restrict__ pred, const int* __restrict__ inst,
    const int* __restrict__ labels, float* __restrict__ ws)
{
    __shared__ float part[128];         // [id 0..15][st 0..7] block partials
    const int b    = blockIdx.y;
    const int tid  = threadIdx.x;
    const int wv   = tid >> 6;          // 0..3
    const int lane = tid & 63;
    const int idb0 = (wv & 1) * 8;      // 0-based first id of this wave's half

    const float* p3 = pred + (size_t)(b * 7 + 3) * DHW;
    const int*   ib = inst   + (size_t)b * DHW;
    const int*   lb = labels + (size_t)b * DHW;
    const int row0 = blockIdx.x * P1_ROWS;

    if (wv < 2) {
        // geometry waves: packed ints G0=Sw|cnt<<17, G1=Sh|Sd<<17 per id.
        // ranges (72 iters): cnt<=72, Sw,Sh<=13752<2^17, Sd<=2232 -> exact.
        unsigned G00=0u,G01=0u,G02=0u,G03=0u,G04=0u,G05=0u,G06=0u,G07=0u;
        unsigned G10=0u,G11=0u,G12=0u,G13=0u,G14=0u,G15=0u,G16=0u,G17=0u;
        float bgacc = 0.f;
        for (int it = 0; it < P1_ITERS; ++it) {
            const int seg = it % 3, r = it / 3;     // uniform (SALU)
            const int row = row0 + r;
            const int w   = seg * 64 + lane;
            const int v   = row * WW + w;
            const int id  = ib[v];
            if (wv == 0) {
                const float seed = fsigmoid(p3[3 * DHW + v]);
                if (lb[v] == 0) bgacc += seed * seed;
            }
            const unsigned p0 = (unsigned)w | (1u << 17);
            const unsigned p1 = (unsigned)(row % HH) | ((unsigned)(row / HH) << 17);
            const int idx = id - 1 - idb0;
            #define GEO(Q) { const bool e = (idx == Q); \
                             G0##Q += e ? p0 : 0u; G1##Q += e ? p1 : 0u; }
            REP8(GEO)
            #undef GEO
        }
        #define GRED(Q) { \
            float c  = wred((float)(G0##Q >> 17)); \
            float sx = wred((float)(G0##Q & 0x1FFFFu) * (1.f / 191.f)); \
            float sy = wred((float)(G1##Q & 0x1FFFFu) * (1.f / 191.f)); \
            float sz = wred((float)(G1##Q >> 17)      * (1.f / 31.f)); \
            if (lane == 0) { float* pp = &part[(idb0 + Q) * 8]; \
                             pp[0] = c; pp[1] = sx; pp[2] = sy; pp[3] = sz; } }
        REP8(GRED)
        #undef GRED
        if (wv == 0) {
            const float r = wred(bgacc);
            if (lane == 0) atomicAdd(&ws[WS_BG8 + b * 8 + (blockIdx.x & 7)], r);
        }
    } else {
        // sigma waves: 4 float accumulators per id, named scalars
        float SA0=0.f,SA1=0.f,SA2=0.f,SA3=0.f,SA4=0.f,SA5=0.f,SA6=0.f,SA7=0.f;
        float SB0=0.f,SB1=0.f,SB2=0.f,SB3=0.f,SB4=0.f,SB5=0.f,SB6=0.f,SB7=0.f;
        float SC0=0.f,SC1=0.f,SC2=0.f,SC3=0.f,SC4=0.f,SC5=0.f,SC6=0.f,SC7=0.f;
        float SD0=0.f,SD1=0.f,SD2=0.f,SD3=0.f,SD4=0.f,SD5=0.f,SD6=0.f,SD7=0.f;
        for (int it = 0; it < P1_ITERS; ++it) {
            const int seg = it % 3, r = it / 3;
            const int v   = (row0 + r) * WW + seg * 64 + lane;
            const int id  = ib[v];
            const float s0 = p3[v], s1 = p3[DHW + v], s2 = p3[2 * DHW + v];
            const float sq = s0 * s0 + s1 * s1 + s2 * s2;
            const int idx = id - 1 - idb0;
            #define SIG(Q) { const float m = (idx == Q) ? 1.f : 0.f; \
                SA##Q = fmaf(m, s0, SA##Q); SB##Q = fmaf(m, s1, SB##Q); \
                SC##Q = fmaf(m, s2, SC##Q); SD##Q = fmaf(m, sq, SD##Q); }
            REP8(SIG)
            #undef SIG
        }
        #define SRED(Q) { \
            float r0 = wred(SA##Q), r1 = wred(SB##Q); \
            float r2 = wred(SC##Q), r3 = wred(SD##Q); \
            if (lane == 0) { float* pp = &part[(idb0 + Q) * 8 + 4]; \
                             pp[0] = r0; pp[1] = r1; pp[2] = r2; pp[3] = r3; } }
        REP8(SRED)
        #undef SRED
    }
    __syncthreads();
    // one coalesced atomic covering 128 consecutive floats (8 lines/block)
    if (tid < 128) {
        const float pv = part[tid];
        if (pv != 0.f) atomicAdd(&ws[WS_STATS + b * 128 + tid], pv);
    }
}

// ---------------- pass 3: staged se + count-only histograms ----------------
// r5-proven structure (4 phases x 4 slots, 16-way rotation, padded cntFB,
// single global histogram). r7 change: per-pair math algebraically reduced:
//   t = 8 - log2e*q2 = C' + sum(B'_i*v_i) + sum(A'_i*v_i^2)   [6 fma]
//   t256 = exp2f(t) = 256*dist                                 [1 v_exp]
// with A' = -log2e*e_i, B' = 2*log2e*e_i*c_i, C' = 8 - log2e*sum(e_i c_i^2)
// folded per id in the prologue. ~13 VALU/pair vs ~17 before.
__global__ __launch_bounds__(256) void pass3_hist(
    const float* __restrict__ pred, const int* __restrict__ inst,
    float* __restrict__ ws)
{
    __shared__ float4 sev[SUBN];              // 16.4 KB (se0,se1,se2,seed|id)
    __shared__ unsigned cntFB[2][NID][KB + 1];// 32.9 KB: x2 replicas, padded
    __shared__ float ctrs[NID][8];
    __shared__ float sred[4];

    const int b   = blockIdx.y;
    const int tid = threadIdx.x;
    const int rep = (tid >> 5) & 1;           // half-wave replica
    const int rot = tid & 15;                 // per-lane id rotation (16-way)

    for (int i = tid; i < 2 * NID * (KB + 1); i += 256) ((unsigned*)cntFB)[i] = 0u;
    if (tid < NID) {
        const float* s = ws + WS_STATS + (size_t)(b * NID + tid) * 8;
        const float cnt = s[0];
        const float safe = fmaxf(cnt, 1.f);
        const float m0 = s[4] / safe, m1 = s[5] / safe, m2 = s[6] / safe;
        const float cx = s[1] / safe, cy = s[2] / safe, cz = s[3] / safe;
        const float e0 = __expf(10.f * m0);
        const float e1 = __expf(10.f * m1);
        const float e2 = __expf(10.f * m2);
        ctrs[tid][0] = 2.f * LOG2E * e0 * cx;               // B'x
        ctrs[tid][1] = 2.f * LOG2E * e1 * cy;               // B'y
        ctrs[tid][2] = 2.f * LOG2E * e2 * cz;               // B'z
        ctrs[tid][3] = -LOG2E * e0;                         // A'x
        ctrs[tid][4] = -LOG2E * e1;                         // A'y
        ctrs[tid][5] = -LOG2E * e2;                         // A'z
        ctrs[tid][6] = 8.f - LOG2E * (e0 * cx * cx + e1 * cy * cy + e2 * cz * cz); // C'
        ctrs[tid][7] = (cnt > 0.f) ? 1.f : 0.f;
    }
    __syncthreads();

    const float* pb = pred + (size_t)b * 7 * DHW;
    const int*   ib = inst + (size_t)b * DHW;

    float sacc = 0.f;
    const int base0 = blockIdx.x * P3_CHUNK;

    for (int sub = 0; sub < SUBT; ++sub) {
        const int vb = base0 + sub * SUBN;
        // ---- phase A: stage se / seed / id ----
        for (int it = 0; it < SUBIT; ++it) {
            const int i = it * 256 + tid;
            const int v = vb + i;
            float x, y, z; xyz_of(v, x, y, z);
            const float se0 = ftanh(pb[v])           + x;
            const float se1 = ftanh(pb[DHW + v])     + y;
            const float se2 = ftanh(pb[2 * DHW + v]) + z;
            const float seed = fsigmoid(pb[6 * DHW + v]);
            const unsigned id = (unsigned)ib[v];
            // pack instance id into low 8 mantissa bits of seed (|err| < 2^-16)
            const unsigned sw = (__float_as_uint(seed) & ~0xFFu) | id;
            sev[i] = make_float4(se0, se1, se2, __uint_as_float(sw));
        }
        __syncthreads();
        // ---- phase B: 4 passes x 4 slots; lane-rotated over ALL 16 ids ----
        for (int p = 0; p < 4; ++p) {
            float b0[4], b1[4], b2[4], a0[4], a1[4], a2[4], cc[4];
            int ip1[4], iidq[4];
            #pragma unroll
            for (int j = 0; j < 4; ++j) {
                const int iid = (p * 4 + j + rot) & 15;
                iidq[j] = iid; ip1[j] = iid + 1;
                b0[j] = ctrs[iid][0]; b1[j] = ctrs[iid][1]; b2[j] = ctrs[iid][2];
                a0[j] = ctrs[iid][3]; a1[j] = ctrs[iid][4]; a2[j] = ctrs[iid][5];
                cc[j] = ctrs[iid][6];
            }
            for (int it = 0; it < SUBIT; ++it) {
                const int i = it * 256 + tid;
                const float4 sv = sev[i];
                const unsigned sw = __float_as_uint(sv.w);
                const int id = (int)(sw & 0xFFu);
                const float seed = sv.w;
                const float vx = sv.x, vy = sv.y, vz = sv.z;
                const float vx2 = vx * vx, vy2 = vy * vy, vz2 = vz * vz;
                #pragma unroll
                for (int j = 0; j < 4; ++j) {
                    float t = fmaf(a0[j], vx2, fmaf(b0[j], vx, cc[j]));
                    t = fmaf(a1[j], vy2, fmaf(b1[j], vy, t));
                    t = fmaf(a2[j], vz2, fmaf(b2[j], vz, t));
                    const float t256 = exp2f(t);          // 256 * dist
                    const bool m = (id == ip1[j]);
                    const float kf = m ? (256.f - t256) : t256;
                    int k = (int)kf;
                    k = min(max(k, 0), KB - 1);
                    // BG in bucket 0 contributes exactly 0 -> skip
                    const unsigned val = m ? 1u : (k ? 0x10000u : 0u);
                    if (m) { const float ds = seed - t256 * (1.f / 256.f); sacc += ds * ds; }
                    if (val) atomicAdd(&cntFB[rep][iidq[j]][k], val);
                }
            }
        }
        __syncthreads();   // also guards cntFB before the merge below
    }

    // merge packed LDS counts (both replicas) -> global float histograms
    float* gh = ws + WS_HIST;
    for (int i = tid; i < NID * KB; i += 256) {
        const int iid = i >> 8, k = i & (KB - 1);
        const unsigned c = cntFB[0][iid][k] + cntFB[1][iid][k];  // fields < 2^15
        float* basep = gh + (size_t)(b * NID + iid) * 2 * KB;
        const float cf = (float)(c & 0xFFFFu);
        const float cb = (float)(c >> 16);
        if (cf != 0.f) atomicAdd(&basep[k], cf);
        if (cb != 0.f) atomicAdd(&basep[KB + k], cb);
    }
    // per-batch seed loss reduce (spread over 8 slots)
    float v = sacc;
    for (int off = 32; off > 0; off >>= 1) v += __shfl_down(v, off, 64);
    if ((tid & 63) == 0) sred[tid >> 6] = v;
    __syncthreads();
    if (tid == 0)
        atomicAdd(&ws[WS_SEED8 + b * 8 + (blockIdx.x & 7)],
                  sred[0] + sred[1] + sred[2] + sred[3]);
}

// ------- pass 4: lovasz from count histograms + fused final assembly -------
__global__ __launch_bounds__(256) void pass4_lovasz(float* __restrict__ ws,
                                                    float* __restrict__ out)
{
    const int t = blockIdx.x;    // (b*16 + iid)
    const int j = threadIdx.x;   // j=0 <-> highest-error bucket
    __shared__ float sF[KB], sB[KB];
    __shared__ double red[KB];
    __shared__ int lastBlk;
    __shared__ float pl[3][4];

    const float P = ws[WS_STATS + t * 8];
    const float* gh = ws + WS_HIST + (size_t)t * 2 * KB;

    const int k = KB - 1 - j;
    const float nF = gh[k], nB = gh[KB + k];
    const float mid = ((float)k + 0.5f) * (1.f / 128.f);
    const float rF = nF * mid, rB = nB * mid;

    sF[j] = nF; sB[j] = nB;
    __syncthreads();
    for (int off = 1; off < KB; off <<= 1) {
        float a = 0.f, c = 0.f;
        if (j >= off) { a = sF[j - off]; c = sB[j - off]; }
        __syncthreads();
        sF[j] += a; sB[j] += c;
        __syncthreads();
    }
    double contrib = 0.0;
    if (P > 0.f) {   // exists == (cnt > 0)
        const double Bb = (double)sB[j] - (double)nB;
        const double U0 = (double)P + Bb;
        const double Fafter = (double)sF[j];
        contrib = (double)rF / U0
                + (double)rB * ((double)P - Fafter) / (U0 * (U0 + (double)nB));
    }
    red[j] = contrib;
    __syncthreads();
    for (int off = KB / 2; off > 0; off >>= 1) {
        if (j < off) red[j] += red[j + off];
        __syncthreads();
    }
    if (j == 0) {
        ws[WS_INSTL + t] = (float)red[0];
        __threadfence();                      // release INSTL before counter
        const unsigned old = atomicAdd((unsigned*)&ws[WS_CTR], 1u);
        lastBlk = (old == 63u) ? 1 : 0;
    }
    __syncthreads();
    if (!lastBlk) return;
    __threadfence();                          // acquire other blocks' INSTL

    // ---- final assembly (last block only) ----
    if (j < 4) {
        float obj = 0.f, v = 0.f, i2 = 0.f;
        for (int i = 0; i < NID; ++i) {
            const int u = j * NID + i;
            const float* s = ws + WS_STATS + (size_t)u * 8;
            const float cnt = s[0];
            i2 += ws[WS_INSTL + u];
            if (cnt > 0.f) {
                obj += 1.f;
                const float m0 = s[4] / cnt, m1 = s[5] / cnt, m2 = s[6] / cnt;
                v += (s[7] - cnt * (m0 * m0 + m1 * m1 + m2 * m2)) / (3.f * cnt);
            }
        }
        float sb = 0.f, bg = 0.f;
        for (int q = 0; q < 8; ++q) {
            sb += ws[WS_SEED8 + j * 8 + q];
            bg += ws[WS_BG8   + j * 8 + q];
        }
        const float denom = fmaxf(obj, 1.f);
        pl[0][j] = i2 / denom;
        pl[1][j] = v / denom;
        pl[2][j] = (sb + bg) / (float)DHW;
    }
    __syncthreads();
    if (j == 0) {
        const float linst = (pl[0][0] + pl[0][1] + pl[0][2] + pl[0][3]) * (1.0f / BB);
        const float lvar  = (pl[1][0] + pl[1][1] + pl[1][2] + pl[1][3]) * (10.0f / BB);
        const float lseed = (pl[2][0] + pl[2][1] + pl[2][2] + pl[2][3]) * (1.0f / BB);
        out[0] = linst;
        out[1] = lvar;
        out[2] = lseed;
        out[3] = linst + lvar + lseed;
    }
}

extern "C" void kernel_launch(void* const* d_in, const int* in_sizes, int n_in,
                              void* d_out, int out_size, void* d_ws, size_t ws_size,
                              hipStream_t stream)
{
    const float* pred   = (const float*)d_in[0];
    const int*   inst   = (const int*)  d_in[1];
    const int*   labels = (const int*)  d_in[2];
    // d_in[3] = center_images (unused), d_in[4] = xyzm (computed analytically)
    float* ws  = (float*)d_ws;
    float* out = (float*)d_out;

    hipMemsetAsync(d_ws, 0, (size_t)WS_TOTAL * sizeof(float), stream);

    dim3 grid1(256, BB);
    dim3 grid3(P3_CHUNKS, BB);
    pass1_stats<<<grid1, 256, 0, stream>>>(pred, inst, labels, ws);
    pass3_hist <<<grid3, 256, 0, stream>>>(pred, inst, ws);
    pass4_lovasz<<<64, KB, 0, stream>>>(ws, out);
}